// Round 2
// baseline (900.708 us; speedup 1.0000x reference)
//
#include <hip/hip_runtime.h>
#include <stdint.h>

typedef unsigned short u16;
typedef __bf16 bf16x8 __attribute__((ext_vector_type(8)));
typedef float f32x4 __attribute__((ext_vector_type(4)));
typedef unsigned short ushort8 __attribute__((ext_vector_type(8)));
typedef unsigned short ushort4v __attribute__((ext_vector_type(4)));

#define MFMA __builtin_amdgcn_mfma_f32_16x16x32_bf16
#define EXP2 __builtin_amdgcn_exp2f

__device__ __forceinline__ u16 f2bf(float f){
  uint32_t u = __builtin_bit_cast(uint32_t, f);
  u += 0x7fffu + ((u >> 16) & 1u);
  return (u16)(u >> 16);
}
__device__ __forceinline__ float bf2f(u16 h){
  uint32_t u = ((uint32_t)h) << 16;
  return __builtin_bit_cast(float, u);
}
__device__ __forceinline__ bf16x8 ld8(const u16* p){
  return __builtin_bit_cast(bf16x8, *(const ushort8*)p);
}
__device__ __forceinline__ void gload16(const void* g, void* l){
  __builtin_amdgcn_global_load_lds((__attribute__((address_space(1))) void*)(void*)g,
                                   (__attribute__((address_space(3))) void*)l, 16, 0, 0);
}

// ---------------- convert / transpose ----------------

__global__ __launch_bounds__(256) void k_conv8(const float* __restrict__ in, u16* __restrict__ out){
  int i = blockIdx.x*256 + threadIdx.x;   // 393216 threads, 8 elems each
  const float4* p = (const float4*)in;
  float4 a = p[i*2], b = p[i*2+1];
  ushort8 o;
  o[0]=f2bf(a.x); o[1]=f2bf(a.y); o[2]=f2bf(a.z); o[3]=f2bf(a.w);
  o[4]=f2bf(b.x); o[5]=f2bf(b.y); o[6]=f2bf(b.z); o[7]=f2bf(b.w);
  ((ushort8*)out)[i] = o;
}

// out[c][r] = in[r][c], f32 -> bf16.  grid (R/64, C/64), 256 thr
__global__ __launch_bounds__(256) void k_tr(const float* __restrict__ in, u16* __restrict__ out,
                                            int R, int Cc){
  __shared__ float tile[64][65];
  int r0 = blockIdx.x*64, c0 = blockIdx.y*64;
  int t = threadIdx.x;
  int c = t & 63, r4 = t >> 6;
  for (int i = 0; i < 16; ++i)
    tile[r4 + i*4][c] = in[(size_t)(r0 + r4 + i*4)*Cc + c0 + c];
  __syncthreads();
  for (int i = 0; i < 16; ++i){
    int rr = r4 + i*4;
    out[(size_t)(c0 + rr)*R + r0 + c] = f2bf(tile[c][rr]);
  }
}

// rel_pos tables * 8 (undo the q-prescale; log2e rides in via Qs), bf16, padded to 128 rows
__global__ __launch_bounds__(256) void k_relconv(const float* __restrict__ rh, const float* __restrict__ rw,
                                                 u16* __restrict__ rh8, u16* __restrict__ rw8){
  int i = blockIdx.x*256 + threadIdx.x;   // 16384
  if (i < 8192)      rh8[i] = f2bf(i < 8128 ? rh[i]*8.0f : 0.0f);
  else { int j = i - 8192; rw8[j] = f2bf(j < 8128 ? rw[j]*8.0f : 0.0f); }
}

// ---------------- QKV GEMM: (4096x768)x(768x2304), split to Qs/K/Vt ----------------

__global__ __launch_bounds__(256) void k_qkv(const u16* __restrict__ X, const u16* __restrict__ WT,
                                             const float* __restrict__ bias,
                                             u16* __restrict__ Qs, u16* __restrict__ Kb, u16* __restrict__ Vt){
  __shared__ __align__(16) u16 At[128*64];
  __shared__ __align__(16) u16 Bt[128*64];
  const int tid = threadIdx.x, lane = tid & 63, w = tid >> 6;
  const int m0 = blockIdx.x*128, n0 = blockIdx.y*128;
  const int wr = (w >> 1)*64, wc = (w & 1)*64;
  const int lr = lane & 15, lg = lane >> 4;
  const int srcRow = w*32 + (lane >> 3);
  const int srcK   = (lane & 7)*8;
  f32x4 acc[4][4] = {};
  for (int kt = 0; kt < 12; ++kt){
    const int kbase = kt*64;
    for (int s = 0; s < 4; ++s){
      gload16(X  + (size_t)(m0 + srcRow + s*8)*768 + kbase + srcK, At + (w*32 + s*8)*64);
      gload16(WT + (size_t)(n0 + srcRow + s*8)*768 + kbase + srcK, Bt + (w*32 + s*8)*64);
    }
    __syncthreads();
    bf16x8 af[2][4], bfr[2][4];
    for (int ks = 0; ks < 2; ++ks)
      for (int i = 0; i < 4; ++i){
        af[ks][i]  = ld8(At + (wr + i*16 + lr)*64 + ks*32 + lg*8);
        bfr[ks][i] = ld8(Bt + (wc + i*16 + lr)*64 + ks*32 + lg*8);
      }
    for (int ks = 0; ks < 2; ++ks)
      for (int mi = 0; mi < 4; ++mi)
        for (int ni = 0; ni < 4; ++ni)
          acc[mi][ni] = MFMA(af[ks][mi], bfr[ks][ni], acc[mi][ni], 0, 0, 0);
    __syncthreads();
  }
  for (int mi = 0; mi < 4; ++mi)
    for (int ni = 0; ni < 4; ++ni){
      int col = n0 + wc + ni*16 + lr;
      int s3 = col / 768, rem = col % 768;
      int hh = rem >> 6, d = rem & 63;
      float bv = bias[col];
      for (int r = 0; r < 4; ++r){
        int row = m0 + wr + mi*16 + lg*4 + r;
        float v = acc[mi][ni][r] + bv;
        // Q pre-scaled by head_dim^-0.5 * log2(e) so softmax runs in exp2 domain
        if      (s3 == 0) Qs[((size_t)hh*4096 + row)*64 + d] = f2bf(v*(0.125f*1.44269504f));
        else if (s3 == 1) Kb[((size_t)hh*4096 + row)*64 + d] = f2bf(v);
        else              Vt[((size_t)hh*64 + d)*4096 + row] = f2bf(v);
      }
    }
}

// ---------------- rel_h / rel_w via MFMA; grid (64 qh, 12 h) ----------------

__global__ __launch_bounds__(256) void k_rel(const u16* __restrict__ Qs, const u16* __restrict__ Rh8,
                                             const u16* __restrict__ Rw8,
                                             u16* __restrict__ relh, u16* __restrict__ relw){
  __shared__ __align__(16) u16 Ql[64*64];
  __shared__ __align__(16) u16 Rhl[64*64];
  __shared__ __align__(16) u16 Rwl[128*64];
  const int tid = threadIdx.x, lane = tid & 63, w = tid >> 6;
  const int qh = blockIdx.x, h = blockIdx.y;
  const int lr = lane & 15, lg = lane >> 4;
  for (int j = 0; j < 2; ++j){
    int ch = tid + 256*j;             // 0..511
    int row = ch >> 3, k8 = (ch & 7)*8;
    *(ushort8*)&Ql[row*64 + k8]  = *(const ushort8*)&Qs[((size_t)h*4096 + qh*64 + row)*64 + k8];
    *(ushort8*)&Rhl[row*64 + k8] = *(const ushort8*)&Rh8[(qh + row)*64 + k8];
  }
  for (int j = 0; j < 4; ++j){
    int ch = tid + 256*j;             // 0..1023
    int row = ch >> 3, k8 = (ch & 7)*8;
    *(ushort8*)&Rwl[row*64 + k8] = *(const ushort8*)&Rw8[row*64 + k8];
  }
  __syncthreads();
  bf16x8 a[2];
  for (int ks = 0; ks < 2; ++ks) a[ks] = ld8(Ql + (w*16 + lr)*64 + ks*32 + lg*8);
  // rel_h[qw][kh] = (Q . rel_pos_h[qh+63-kh]) ; computed as Q @ Rh[qh+c]^T, kh = 63-c
  for (int ct = 0; ct < 4; ++ct){
    f32x4 c = {};
    for (int ks = 0; ks < 2; ++ks)
      c = MFMA(a[ks], ld8(Rhl + (ct*16 + lr)*64 + ks*32 + lg*8), c, 0, 0, 0);
    int kh = 63 - (ct*16 + lr);
    for (int r = 0; r < 4; ++r){
      int qw = w*16 + lg*4 + r;
      relh[((size_t)h*4096 + qh*64 + qw)*64 + kh] = f2bf(c[r]);
    }
  }
  // rel_w[qw][kw] = (Q . rel_pos_w[qw+63-kw]) ; full band, keep valid kw
  for (int ct = 0; ct < 8; ++ct){
    f32x4 c = {};
    for (int ks = 0; ks < 2; ++ks)
      c = MFMA(a[ks], ld8(Rwl + (ct*16 + lr)*64 + ks*32 + lg*8), c, 0, 0, 0);
    int cc = ct*16 + lr;
    for (int r = 0; r < 4; ++r){
      int qw = w*16 + lg*4 + r;
      int kw = qw + 63 - cc;
      if (kw >= 0 && kw < 64)
        relw[((size_t)h*4096 + qh*64 + qw)*64 + kw] = f2bf(c[r]);
    }
  }
}

// ---------------- flash attention; grid (256 q-tiles, 12 heads), 4 waves ----------------
// All 4 waves share the SAME 16 q-rows; each wave handles 16 of the 64 KV tiles
// (intra-block flash-decoding split), merged through LDS at block end.
// 12288 waves total -> 32 waves/CU cap -> ~full occupancy (was 35%).

__global__ __launch_bounds__(256, 8) void k_flash(const u16* __restrict__ Qs, const u16* __restrict__ Kb,
                                                  const u16* __restrict__ Vt,
                                                  const u16* __restrict__ relh, const u16* __restrict__ relw,
                                                  u16* __restrict__ Ob){
  // per wave: first 2KB is the P staging tile during the loop; at merge time the
  // same 4224B region holds O[16][64] f32 (4096B) + m[16] (64B) + l[16] (64B).
  __shared__ __align__(16) char SM[4][4224];
  const int tid = threadIdx.x, lane = tid & 63, w = tid >> 6;
  const int qt = blockIdx.x, h = blockIdx.y;
  const int lr = lane & 15, lg = lane >> 4;
  const size_t hq = (size_t)h*4096;

  bf16x8 qf[2];
  {
    int qA = qt*16 + lr;
    qf[0] = ld8(Qs + (hq + qA)*64 + lg*8);
    qf[1] = ld8(Qs + (hq + qA)*64 + 32 + lg*8);
  }
  int qC[4];
  for (int r = 0; r < 4; ++r) qC[r] = qt*16 + lg*4 + r;
  float rw_reg[4][4];
  for (int ct = 0; ct < 4; ++ct)
    for (int r = 0; r < 4; ++r)
      rw_reg[ct][r] = bf2f(relw[(hq + qC[r])*64 + ct*16 + lr]);

  float m[4], lsum[4] = {0.f, 0.f, 0.f, 0.f};
  for (int r = 0; r < 4; ++r) m[r] = -1e30f;
  f32x4 oacc[4] = {};
  char* Pb = SM[w];

  for (int i = 0; i < 16; ++i){
    const int kb = w*16 + i;
    f32x4 s[4] = {};
    for (int ct = 0; ct < 4; ++ct){
      const u16* kp = Kb + (hq + kb*64 + ct*16 + lr)*64 + lg*8;
      s[ct] = MFMA(qf[0], ld8(kp),      s[ct], 0, 0, 0);
      s[ct] = MFMA(qf[1], ld8(kp + 32), s[ct], 0, 0, 0);
    }
    float rh_r[4];
    for (int r = 0; r < 4; ++r) rh_r[r] = bf2f(relh[(hq + qC[r])*64 + kb]);
    float pm[4];
    for (int r = 0; r < 4; ++r){
      s[0][r] += rh_r[r] + rw_reg[0][r];
      s[1][r] += rh_r[r] + rw_reg[1][r];
      s[2][r] += rh_r[r] + rw_reg[2][r];
      s[3][r] += rh_r[r] + rw_reg[3][r];
      pm[r] = fmaxf(fmaxf(s[0][r], s[1][r]), fmaxf(s[2][r], s[3][r]));
    }
    for (int msk = 1; msk < 16; msk <<= 1)
      for (int r = 0; r < 4; ++r) pm[r] = fmaxf(pm[r], __shfl_xor(pm[r], msk, 64));
    float corr[4], rs[4];
    for (int r = 0; r < 4; ++r){
      float nm = fmaxf(m[r], pm[r]);
      corr[r] = EXP2(m[r] - nm);
      m[r] = nm;
      rs[r] = 0.f;
    }
    for (int ct = 0; ct < 4; ++ct)
      for (int r = 0; r < 4; ++r){
        float p = EXP2(s[ct][r] - m[r]);
        s[ct][r] = p; rs[r] += p;
      }
    for (int msk = 1; msk < 16; msk <<= 1)
      for (int r = 0; r < 4; ++r) rs[r] += __shfl_xor(rs[r], msk, 64);
    for (int r = 0; r < 4; ++r) lsum[r] = lsum[r]*corr[r] + rs[r];
    for (int dt = 0; dt < 4; ++dt)
      for (int r = 0; r < 4; ++r) oacc[dt][r] *= corr[r];
    // P -> LDS (XOR-swizzled to kill 16-way bank conflict on the b128 reads)
    for (int ct = 0; ct < 4; ++ct)
      for (int r = 0; r < 4; ++r){
        int prow = lg*4 + r, pcol = ct*16 + lr;
        int off = (prow*128 + pcol*2) ^ ((prow & 7) << 4);
        *(u16*)(Pb + off) = f2bf(s[ct][r]);
      }
    bf16x8 pa[2];
    for (int ks = 0; ks < 2; ++ks){
      int off = (lr*128 + (ks*32 + lg*8)*2) ^ ((lr & 7) << 4);
      pa[ks] = __builtin_bit_cast(bf16x8, *(ushort8*)(Pb + off));
    }
    for (int dt = 0; dt < 4; ++dt){
      const u16* vp = Vt + ((size_t)h*64 + dt*16 + lr)*4096 + kb*64 + lg*8;
      oacc[dt] = MFMA(pa[0], ld8(vp),      oacc[dt], 0, 0, 0);
      oacc[dt] = MFMA(pa[1], ld8(vp + 32), oacc[dt], 0, 0, 0);
    }
  }

  // ---- intra-block merge of the 4 KV-split partials ----
  {
    float* Ow = (float*)SM[w];
    for (int dt = 0; dt < 4; ++dt)
      for (int r = 0; r < 4; ++r)
        Ow[(lg*4 + r)*64 + dt*16 + lr] = oacc[dt][r];
    if (lr == 0){
      float* Mw = (float*)(SM[w] + 4096);
      float* Lw = (float*)(SM[w] + 4160);
      for (int r = 0; r < 4; ++r){
        Mw[lg*4 + r] = m[r];
        Lw[lg*4 + r] = lsum[r];
      }
    }
  }
  __syncthreads();
  {
    const int q = tid >> 4, dg = tid & 15;
    float mw[4], lw[4];
    float mstar = -1e30f;
    #pragma unroll
    for (int ww = 0; ww < 4; ++ww){
      mw[ww] = ((const float*)(SM[ww] + 4096))[q];
      lw[ww] = ((const float*)(SM[ww] + 4160))[q];
      mstar = fmaxf(mstar, mw[ww]);
    }
    float scl[4], lstar = 0.f;
    #pragma unroll
    for (int ww = 0; ww < 4; ++ww){
      scl[ww] = EXP2(mw[ww] - mstar);
      lstar += scl[ww]*lw[ww];
    }
    f32x4 o = {};
    #pragma unroll
    for (int ww = 0; ww < 4; ++ww){
      f32x4 ov = *(const f32x4*)(SM[ww] + (q*64 + dg*4)*4);
      o[0] += scl[ww]*ov[0]; o[1] += scl[ww]*ov[1];
      o[2] += scl[ww]*ov[2]; o[3] += scl[ww]*ov[3];
    }
    const float inv = 1.0f / lstar;
    ushort4v pk;
    pk[0] = f2bf(o[0]*inv); pk[1] = f2bf(o[1]*inv);
    pk[2] = f2bf(o[2]*inv); pk[3] = f2bf(o[3]*inv);
    *(ushort4v*)&Ob[(size_t)(qt*16 + q)*768 + h*64 + dg*4] = pk;
  }
}

// ---------------- proj GEMM: (4096x768)x(768x768) + b -> f32 out ----------------

__global__ __launch_bounds__(256) void k_proj(const u16* __restrict__ A, const u16* __restrict__ WT,
                                              const float* __restrict__ bias, float* __restrict__ out){
  __shared__ __align__(16) u16 At[128*64];
  __shared__ __align__(16) u16 Bt[128*64];
  const int tid = threadIdx.x, lane = tid & 63, w = tid >> 6;
  const int m0 = blockIdx.x*128, n0 = blockIdx.y*128;
  const int wr = (w >> 1)*64, wc = (w & 1)*64;
  const int lr = lane & 15, lg = lane >> 4;
  const int srcRow = w*32 + (lane >> 3);
  const int srcK   = (lane & 7)*8;
  f32x4 acc[4][4] = {};
  for (int kt = 0; kt < 12; ++kt){
    const int kbase = kt*64;
    for (int s = 0; s < 4; ++s){
      gload16(A  + (size_t)(m0 + srcRow + s*8)*768 + kbase + srcK, At + (w*32 + s*8)*64);
      gload16(WT + (size_t)(n0 + srcRow + s*8)*768 + kbase + srcK, Bt + (w*32 + s*8)*64);
    }
    __syncthreads();
    bf16x8 af[2][4], bfr[2][4];
    for (int ks = 0; ks < 2; ++ks)
      for (int i = 0; i < 4; ++i){
        af[ks][i]  = ld8(At + (wr + i*16 + lr)*64 + ks*32 + lg*8);
        bfr[ks][i] = ld8(Bt + (wc + i*16 + lr)*64 + ks*32 + lg*8);
      }
    for (int ks = 0; ks < 2; ++ks)
      for (int mi = 0; mi < 4; ++mi)
        for (int ni = 0; ni < 4; ++ni)
          acc[mi][ni] = MFMA(af[ks][mi], bfr[ks][ni], acc[mi][ni], 0, 0, 0);
    __syncthreads();
  }
  for (int mi = 0; mi < 4; ++mi)
    for (int ni = 0; ni < 4; ++ni){
      int col = n0 + wc + ni*16 + lr;
      float bv = bias[col];
      for (int r = 0; r < 4; ++r){
        int row = m0 + wr + mi*16 + lg*4 + r;
        out[(size_t)row*768 + col] = acc[mi][ni][r] + bv;
      }
    }
}

// ---------------- launch ----------------

extern "C" void kernel_launch(void* const* d_in, const int* in_sizes, int n_in,
                              void* d_out, int out_size, void* d_ws, size_t ws_size,
                              hipStream_t stream){
  const float* X32   = (const float*)d_in[0];
  const float* qkvw  = (const float*)d_in[1];
  const float* qkvb  = (const float*)d_in[2];
  const float* projw = (const float*)d_in[3];
  const float* projb = (const float*)d_in[4];
  const float* rposh = (const float*)d_in[5];
  const float* rposw = (const float*)d_in[6];

  u16* Xb  = (u16*)d_ws;            // 4096*768
  u16* W1T = Xb  + 3145728;         // 2304*768
  u16* PT  = W1T + 1769472;         // 768*768
  u16* Rh8 = PT  + 589824;          // 128*64 (padded)
  u16* Rw8 = Rh8 + 8192;            // 128*64 (padded)
  u16* Qs  = Rw8 + 8192;            // 12*4096*64 (pre-scaled by 1/8 * log2e)
  u16* Kb  = Qs  + 3145728;
  u16* Vt  = Kb  + 3145728;         // [12][64][4096] transposed
  u16* Rlh = Vt  + 3145728;         // [12][4096][64]
  u16* Rlw = Rlh + 3145728;         // [12][4096][64]
  u16* Ob  = Rlw + 3145728;         // [4096][768]
  float* out = (float*)d_out;

  k_conv8  <<<1536, 256, 0, stream>>>(X32, Xb);
  k_tr     <<<dim3(12, 36), 256, 0, stream>>>(qkvw, W1T, 768, 2304);
  k_tr     <<<dim3(12, 12), 256, 0, stream>>>(projw, PT, 768, 768);
  k_relconv<<<64, 256, 0, stream>>>(rposh, rposw, Rh8, Rw8);
  k_qkv    <<<dim3(32, 18), 256, 0, stream>>>(Xb, W1T, qkvb, Qs, Kb, Vt);
  k_rel    <<<dim3(64, 12), 256, 0, stream>>>(Qs, Rh8, Rw8, Rlh, Rlw);
  k_flash  <<<dim3(256, 12), 256, 0, stream>>>(Qs, Kb, Vt, Rlh, Rlw, Ob);
  k_proj   <<<dim3(32, 6), 256, 0, stream>>>(Ob, PT, projb, out);
}

// Round 3
// 441.918 us; speedup vs baseline: 2.0382x; 2.0382x over previous
//
#include <hip/hip_runtime.h>
#include <stdint.h>

typedef unsigned short u16;
typedef __bf16 bf16x8 __attribute__((ext_vector_type(8)));
typedef float f32x4 __attribute__((ext_vector_type(4)));
typedef unsigned short ushort8 __attribute__((ext_vector_type(8)));
typedef unsigned short ushort4v __attribute__((ext_vector_type(4)));

#define MFMA __builtin_amdgcn_mfma_f32_16x16x32_bf16
#define EXP2 __builtin_amdgcn_exp2f

__device__ __forceinline__ u16 f2bf(float f){
  uint32_t u = __builtin_bit_cast(uint32_t, f);
  u += 0x7fffu + ((u >> 16) & 1u);
  return (u16)(u >> 16);
}
__device__ __forceinline__ float bf2f(u16 h){
  uint32_t u = ((uint32_t)h) << 16;
  return __builtin_bit_cast(float, u);
}
__device__ __forceinline__ bf16x8 ld8(const u16* p){
  return __builtin_bit_cast(bf16x8, *(const ushort8*)p);
}
__device__ __forceinline__ void gload16(const void* g, void* l){
  __builtin_amdgcn_global_load_lds((__attribute__((address_space(1))) void*)(void*)g,
                                   (__attribute__((address_space(3))) void*)l, 16, 0, 0);
}

// ---------------- convert / transpose ----------------

__global__ __launch_bounds__(256) void k_conv8(const float* __restrict__ in, u16* __restrict__ out){
  int i = blockIdx.x*256 + threadIdx.x;   // 393216 threads, 8 elems each
  const float4* p = (const float4*)in;
  float4 a = p[i*2], b = p[i*2+1];
  ushort8 o;
  o[0]=f2bf(a.x); o[1]=f2bf(a.y); o[2]=f2bf(a.z); o[3]=f2bf(a.w);
  o[4]=f2bf(b.x); o[5]=f2bf(b.y); o[6]=f2bf(b.z); o[7]=f2bf(b.w);
  ((ushort8*)out)[i] = o;
}

// out[c][r] = in[r][c], f32 -> bf16.  grid (R/64, C/64), 256 thr
__global__ __launch_bounds__(256) void k_tr(const float* __restrict__ in, u16* __restrict__ out,
                                            int R, int Cc){
  __shared__ float tile[64][65];
  int r0 = blockIdx.x*64, c0 = blockIdx.y*64;
  int t = threadIdx.x;
  int c = t & 63, r4 = t >> 6;
  for (int i = 0; i < 16; ++i)
    tile[r4 + i*4][c] = in[(size_t)(r0 + r4 + i*4)*Cc + c0 + c];
  __syncthreads();
  for (int i = 0; i < 16; ++i){
    int rr = r4 + i*4;
    out[(size_t)(c0 + rr)*R + r0 + c] = f2bf(tile[c][rr]);
  }
}

// rel_pos tables * 8 (undo the q-prescale; log2e rides in via Qs), bf16, padded to 128 rows
__global__ __launch_bounds__(256) void k_relconv(const float* __restrict__ rh, const float* __restrict__ rw,
                                                 u16* __restrict__ rh8, u16* __restrict__ rw8){
  int i = blockIdx.x*256 + threadIdx.x;   // 16384
  if (i < 8192)      rh8[i] = f2bf(i < 8128 ? rh[i]*8.0f : 0.0f);
  else { int j = i - 8192; rw8[j] = f2bf(j < 8128 ? rw[j]*8.0f : 0.0f); }
}

// ---------------- QKV GEMM: (4096x768)x(768x2304), split to Qs/K/Vt ----------------

__global__ __launch_bounds__(256) void k_qkv(const u16* __restrict__ X, const u16* __restrict__ WT,
                                             const float* __restrict__ bias,
                                             u16* __restrict__ Qs, u16* __restrict__ Kb, u16* __restrict__ Vt){
  __shared__ __align__(16) u16 At[128*64];
  __shared__ __align__(16) u16 Bt[128*64];
  const int tid = threadIdx.x, lane = tid & 63, w = tid >> 6;
  const int m0 = blockIdx.x*128, n0 = blockIdx.y*128;
  const int wr = (w >> 1)*64, wc = (w & 1)*64;
  const int lr = lane & 15, lg = lane >> 4;
  const int srcRow = w*32 + (lane >> 3);
  const int srcK   = (lane & 7)*8;
  f32x4 acc[4][4] = {};
  for (int kt = 0; kt < 12; ++kt){
    const int kbase = kt*64;
    for (int s = 0; s < 4; ++s){
      gload16(X  + (size_t)(m0 + srcRow + s*8)*768 + kbase + srcK, At + (w*32 + s*8)*64);
      gload16(WT + (size_t)(n0 + srcRow + s*8)*768 + kbase + srcK, Bt + (w*32 + s*8)*64);
    }
    __syncthreads();
    bf16x8 af[2][4], bfr[2][4];
    for (int ks = 0; ks < 2; ++ks)
      for (int i = 0; i < 4; ++i){
        af[ks][i]  = ld8(At + (wr + i*16 + lr)*64 + ks*32 + lg*8);
        bfr[ks][i] = ld8(Bt + (wc + i*16 + lr)*64 + ks*32 + lg*8);
      }
    for (int ks = 0; ks < 2; ++ks)
      for (int mi = 0; mi < 4; ++mi)
        for (int ni = 0; ni < 4; ++ni)
          acc[mi][ni] = MFMA(af[ks][mi], bfr[ks][ni], acc[mi][ni], 0, 0, 0);
    __syncthreads();
  }
  for (int mi = 0; mi < 4; ++mi)
    for (int ni = 0; ni < 4; ++ni){
      int col = n0 + wc + ni*16 + lr;
      int s3 = col / 768, rem = col % 768;
      int hh = rem >> 6, d = rem & 63;
      float bv = bias[col];
      for (int r = 0; r < 4; ++r){
        int row = m0 + wr + mi*16 + lg*4 + r;
        float v = acc[mi][ni][r] + bv;
        // Q pre-scaled by head_dim^-0.5 * log2(e) so softmax runs in exp2 domain
        if      (s3 == 0) Qs[((size_t)hh*4096 + row)*64 + d] = f2bf(v*(0.125f*1.44269504f));
        else if (s3 == 1) Kb[((size_t)hh*4096 + row)*64 + d] = f2bf(v);
        else              Vt[((size_t)hh*64 + d)*4096 + row] = f2bf(v);
      }
    }
}

// ---------------- rel_h / rel_w via MFMA; grid (64 qh, 12 h) ----------------

__global__ __launch_bounds__(256) void k_rel(const u16* __restrict__ Qs, const u16* __restrict__ Rh8,
                                             const u16* __restrict__ Rw8,
                                             u16* __restrict__ relh, u16* __restrict__ relw){
  __shared__ __align__(16) u16 Ql[64*64];
  __shared__ __align__(16) u16 Rhl[64*64];
  __shared__ __align__(16) u16 Rwl[128*64];
  const int tid = threadIdx.x, lane = tid & 63, w = tid >> 6;
  const int qh = blockIdx.x, h = blockIdx.y;
  const int lr = lane & 15, lg = lane >> 4;
  for (int j = 0; j < 2; ++j){
    int ch = tid + 256*j;             // 0..511
    int row = ch >> 3, k8 = (ch & 7)*8;
    *(ushort8*)&Ql[row*64 + k8]  = *(const ushort8*)&Qs[((size_t)h*4096 + qh*64 + row)*64 + k8];
    *(ushort8*)&Rhl[row*64 + k8] = *(const ushort8*)&Rh8[(qh + row)*64 + k8];
  }
  for (int j = 0; j < 4; ++j){
    int ch = tid + 256*j;             // 0..1023
    int row = ch >> 3, k8 = (ch & 7)*8;
    *(ushort8*)&Rwl[row*64 + k8] = *(const ushort8*)&Rw8[row*64 + k8];
  }
  __syncthreads();
  bf16x8 a[2];
  for (int ks = 0; ks < 2; ++ks) a[ks] = ld8(Ql + (w*16 + lr)*64 + ks*32 + lg*8);
  // rel_h[qw][kh] = (Q . rel_pos_h[qh+63-kh]) ; computed as Q @ Rh[qh+c]^T, kh = 63-c
  for (int ct = 0; ct < 4; ++ct){
    f32x4 c = {};
    for (int ks = 0; ks < 2; ++ks)
      c = MFMA(a[ks], ld8(Rhl + (ct*16 + lr)*64 + ks*32 + lg*8), c, 0, 0, 0);
    int kh = 63 - (ct*16 + lr);
    for (int r = 0; r < 4; ++r){
      int qw = w*16 + lg*4 + r;
      relh[((size_t)h*4096 + qh*64 + qw)*64 + kh] = f2bf(c[r]);
    }
  }
  // rel_w[qw][kw] = (Q . rel_pos_w[qw+63-kw]) ; full band, keep valid kw
  for (int ct = 0; ct < 8; ++ct){
    f32x4 c = {};
    for (int ks = 0; ks < 2; ++ks)
      c = MFMA(a[ks], ld8(Rwl + (ct*16 + lr)*64 + ks*32 + lg*8), c, 0, 0, 0);
    int cc = ct*16 + lr;
    for (int r = 0; r < 4; ++r){
      int qw = w*16 + lg*4 + r;
      int kw = qw + 63 - cc;
      if (kw >= 0 && kw < 64)
        relw[((size_t)h*4096 + qh*64 + qw)*64 + kw] = f2bf(c[r]);
    }
  }
}

// ---------------- flash attention; grid (64 qblocks, 12 heads), 4 waves ----------------
// Swapped-operand layout: QK^T computed as mfma(K,Q) -> S^T (col = q = lane&15),
// so softmax is per-lane over 16 own values + two shfl_xor(16/32); PV computed as
// mfma(V^T, P^T) -> O^T so the online rescale stays fully in-lane.
// K double-buffered in regs (next tile prefetched during softmax); V prefetched at
// iteration top (consumed after softmax) -> global latency hidden under compute.

__global__ __launch_bounds__(256, 3) void k_flash(const u16* __restrict__ Qs, const u16* __restrict__ Kb,
                                                  const u16* __restrict__ Vt,
                                                  const u16* __restrict__ relh, const u16* __restrict__ relw,
                                                  u16* __restrict__ Ob){
  __shared__ __align__(16) char SM[4][2048];   // per-wave P tile [16 q][64 k] bf16, XOR-swizzled
  const int tid = threadIdx.x, lane = tid & 63, w = tid >> 6;
  const int qb = blockIdx.x, h = blockIdx.y;
  const int lr = lane & 15, lg = lane >> 4;
  const size_t hq = (size_t)h*4096;
  const int q = qb*64 + w*16 + lr;             // this lane's q row (S^T column)
  char* Pb = SM[w];
  const int swz = (lr & 7) << 4;

  const bf16x8 qf0 = ld8(Qs + (hq + q)*64 + lg*8);
  const bf16x8 qf1 = ld8(Qs + (hq + q)*64 + 32 + lg*8);
  ushort4v rwp[4];
  #pragma unroll
  for (int ct = 0; ct < 4; ++ct)
    rwp[ct] = *(const ushort4v*)&relw[(hq + q)*64 + ct*16 + lg*4];

  const u16* Kbase  = Kb + hq*64 + lg*8;                    // + (kb*64+ct*16+lr)*64 [+32]
  const u16* Vbase  = Vt + (size_t)h*64*4096 + lg*8;        // + (dt*16+lr)*4096 + kb*64 [+32]
  const u16* rhbase = relh + (hq + q)*64;

  float m = -1e30f, lsum = 0.f;
  f32x4 oacc[4] = {};                          // O^T tiles: rows d = dt*16+lg*4+r, col q = lr
  bf16x8 kA[8], kB[8], vv[8];

  auto loadK = [&](bf16x8 (&dst)[8], int kbi){
    const u16* kp = Kbase + (size_t)(kbi*64)*64;
    #pragma unroll
    for (int ct = 0; ct < 4; ++ct){
      dst[ct*2]   = ld8(kp + (ct*16 + lr)*64);
      dst[ct*2+1] = ld8(kp + (ct*16 + lr)*64 + 32);
    }
  };
  auto iter = [&](int kb, const bf16x8 (&KC)[8], bf16x8 (&KN)[8]){
    // V for this tile: issue now, consumed after softmax
    #pragma unroll
    for (int dt = 0; dt < 4; ++dt){
      const u16* vp = Vbase + (size_t)(dt*16 + lr)*4096 + kb*64;
      vv[dt*2]   = ld8(vp);
      vv[dt*2+1] = ld8(vp + 32);
    }
    // S^T = K·Q^T, acc pre-seeded with bias rel_h[q][kb] + rel_w[q][k]
    const float rhv = bf2f(rhbase[kb]);
    f32x4 s[4];
    #pragma unroll
    for (int ct = 0; ct < 4; ++ct)
      #pragma unroll
      for (int r = 0; r < 4; ++r)
        s[ct][r] = rhv + bf2f(rwp[ct][r]);
    #pragma unroll
    for (int ct = 0; ct < 4; ++ct){
      s[ct] = MFMA(KC[ct*2],   qf0, s[ct], 0, 0, 0);
      s[ct] = MFMA(KC[ct*2+1], qf1, s[ct], 0, 0, 0);
    }
    // prefetch next K tile; latency hides under softmax + P round-trip
    loadK(KN, (kb + 1) & 63);
    // per-lane softmax over this lane's 16 k-values, then reduce across lg
    float t0 = fmaxf(fmaxf(s[0][0], s[0][1]), fmaxf(s[0][2], s[0][3]));
    float t1 = fmaxf(fmaxf(s[1][0], s[1][1]), fmaxf(s[1][2], s[1][3]));
    float t2 = fmaxf(fmaxf(s[2][0], s[2][1]), fmaxf(s[2][2], s[2][3]));
    float t3 = fmaxf(fmaxf(s[3][0], s[3][1]), fmaxf(s[3][2], s[3][3]));
    float pm = fmaxf(fmaxf(t0, t1), fmaxf(t2, t3));
    pm = fmaxf(pm, __shfl_xor(pm, 16, 64));
    pm = fmaxf(pm, __shfl_xor(pm, 32, 64));
    const float nm = fmaxf(m, pm);
    const float corr = EXP2(m - nm);
    m = nm;
    float rs = 0.f;
    #pragma unroll
    for (int ct = 0; ct < 4; ++ct)
      #pragma unroll
      for (int r = 0; r < 4; ++r){
        float p = EXP2(s[ct][r] - m);
        s[ct][r] = p; rs += p;
      }
    rs += __shfl_xor(rs, 16, 64);
    rs += __shfl_xor(rs, 32, 64);
    lsum = lsum*corr + rs;
    #pragma unroll
    for (int dt = 0; dt < 4; ++dt)
      #pragma unroll
      for (int r = 0; r < 4; ++r) oacc[dt][r] *= corr;
    // P[q][k] -> LDS (packed b64 writes, XOR-swizzled), then read back as P^T b-frags
    #pragma unroll
    for (int ct = 0; ct < 4; ++ct){
      uint2 uv;
      uv.x = (uint32_t)f2bf(s[ct][0]) | ((uint32_t)f2bf(s[ct][1]) << 16);
      uv.y = (uint32_t)f2bf(s[ct][2]) | ((uint32_t)f2bf(s[ct][3]) << 16);
      *(uint2*)(Pb + ((lr*128 + ct*32 + lg*8) ^ swz)) = uv;
    }
    bf16x8 pa0 = __builtin_bit_cast(bf16x8, *(ushort8*)(Pb + ((lr*128      + lg*16) ^ swz)));
    bf16x8 pa1 = __builtin_bit_cast(bf16x8, *(ushort8*)(Pb + ((lr*128 + 64 + lg*16) ^ swz)));
    // O^T += V^T · P^T
    #pragma unroll
    for (int dt = 0; dt < 4; ++dt){
      oacc[dt] = MFMA(vv[dt*2],   pa0, oacc[dt], 0, 0, 0);
      oacc[dt] = MFMA(vv[dt*2+1], pa1, oacc[dt], 0, 0, 0);
    }
  };

  loadK(kA, 0);
  for (int kb2 = 0; kb2 < 64; kb2 += 2){
    iter(kb2,     kA, kB);
    iter(kb2 + 1, kB, kA);
  }

  const float inv = 1.0f / lsum;
  #pragma unroll
  for (int dt = 0; dt < 4; ++dt){
    ushort4v pk;
    #pragma unroll
    for (int r = 0; r < 4; ++r) pk[r] = f2bf(oacc[dt][r]*inv);
    *(ushort4v*)&Ob[(size_t)q*768 + h*64 + dt*16 + lg*4] = pk;
  }
}

// ---------------- proj GEMM: (4096x768)x(768x768) + b -> f32 out ----------------

__global__ __launch_bounds__(256) void k_proj(const u16* __restrict__ A, const u16* __restrict__ WT,
                                              const float* __restrict__ bias, float* __restrict__ out){
  __shared__ __align__(16) u16 At[128*64];
  __shared__ __align__(16) u16 Bt[128*64];
  const int tid = threadIdx.x, lane = tid & 63, w = tid >> 6;
  const int m0 = blockIdx.x*128, n0 = blockIdx.y*128;
  const int wr = (w >> 1)*64, wc = (w & 1)*64;
  const int lr = lane & 15, lg = lane >> 4;
  const int srcRow = w*32 + (lane >> 3);
  const int srcK   = (lane & 7)*8;
  f32x4 acc[4][4] = {};
  for (int kt = 0; kt < 12; ++kt){
    const int kbase = kt*64;
    for (int s = 0; s < 4; ++s){
      gload16(A  + (size_t)(m0 + srcRow + s*8)*768 + kbase + srcK, At + (w*32 + s*8)*64);
      gload16(WT + (size_t)(n0 + srcRow + s*8)*768 + kbase + srcK, Bt + (w*32 + s*8)*64);
    }
    __syncthreads();
    bf16x8 af[2][4], bfr[2][4];
    for (int ks = 0; ks < 2; ++ks)
      for (int i = 0; i < 4; ++i){
        af[ks][i]  = ld8(At + (wr + i*16 + lr)*64 + ks*32 + lg*8);
        bfr[ks][i] = ld8(Bt + (wc + i*16 + lr)*64 + ks*32 + lg*8);
      }
    for (int ks = 0; ks < 2; ++ks)
      for (int mi = 0; mi < 4; ++mi)
        for (int ni = 0; ni < 4; ++ni)
          acc[mi][ni] = MFMA(af[ks][mi], bfr[ks][ni], acc[mi][ni], 0, 0, 0);
    __syncthreads();
  }
  for (int mi = 0; mi < 4; ++mi)
    for (int ni = 0; ni < 4; ++ni){
      int col = n0 + wc + ni*16 + lr;
      float bv = bias[col];
      for (int r = 0; r < 4; ++r){
        int row = m0 + wr + mi*16 + lg*4 + r;
        out[(size_t)row*768 + col] = acc[mi][ni][r] + bv;
      }
    }
}

// ---------------- launch ----------------

extern "C" void kernel_launch(void* const* d_in, const int* in_sizes, int n_in,
                              void* d_out, int out_size, void* d_ws, size_t ws_size,
                              hipStream_t stream){
  const float* X32   = (const float*)d_in[0];
  const float* qkvw  = (const float*)d_in[1];
  const float* qkvb  = (const float*)d_in[2];
  const float* projw = (const float*)d_in[3];
  const float* projb = (const float*)d_in[4];
  const float* rposh = (const float*)d_in[5];
  const float* rposw = (const float*)d_in[6];

  u16* Xb  = (u16*)d_ws;            // 4096*768
  u16* W1T = Xb  + 3145728;         // 2304*768
  u16* PT  = W1T + 1769472;         // 768*768
  u16* Rh8 = PT  + 589824;          // 128*64 (padded)
  u16* Rw8 = Rh8 + 8192;            // 128*64 (padded)
  u16* Qs  = Rw8 + 8192;            // 12*4096*64 (pre-scaled by 1/8 * log2e)
  u16* Kb  = Qs  + 3145728;
  u16* Vt  = Kb  + 3145728;         // [12][64][4096] transposed
  u16* Rlh = Vt  + 3145728;         // [12][4096][64]
  u16* Rlw = Rlh + 3145728;         // [12][4096][64]
  u16* Ob  = Rlw + 3145728;         // [4096][768]
  float* out = (float*)d_out;

  k_conv8  <<<1536, 256, 0, stream>>>(X32, Xb);
  k_tr     <<<dim3(12, 36), 256, 0, stream>>>(qkvw, W1T, 768, 2304);
  k_tr     <<<dim3(12, 12), 256, 0, stream>>>(projw, PT, 768, 768);
  k_relconv<<<64, 256, 0, stream>>>(rposh, rposw, Rh8, Rw8);
  k_qkv    <<<dim3(32, 18), 256, 0, stream>>>(Xb, W1T, qkvb, Qs, Kb, Vt);
  k_rel    <<<dim3(64, 12), 256, 0, stream>>>(Qs, Rh8, Rw8, Rlh, Rlw);
  k_flash  <<<dim3(64, 12), 256, 0, stream>>>(Qs, Kb, Vt, Rlh, Rlw, Ob);
  k_proj   <<<dim3(32, 6), 256, 0, stream>>>(Ob, PT, projb, out);
}

// Round 4
// 432.471 us; speedup vs baseline: 2.0827x; 1.0218x over previous
//
#include <hip/hip_runtime.h>
#include <stdint.h>

typedef unsigned short u16;
typedef __bf16 bf16x8 __attribute__((ext_vector_type(8)));
typedef float f32x4 __attribute__((ext_vector_type(4)));
typedef unsigned short ushort8 __attribute__((ext_vector_type(8)));
typedef unsigned short ushort4v __attribute__((ext_vector_type(4)));

#define MFMA __builtin_amdgcn_mfma_f32_16x16x32_bf16
#define EXP2 __builtin_amdgcn_exp2f

__device__ __forceinline__ u16 f2bf(float f){
  uint32_t u = __builtin_bit_cast(uint32_t, f);
  u += 0x7fffu + ((u >> 16) & 1u);
  return (u16)(u >> 16);
}
__device__ __forceinline__ float bf2f(u16 h){
  uint32_t u = ((uint32_t)h) << 16;
  return __builtin_bit_cast(float, u);
}
__device__ __forceinline__ bf16x8 ld8(const u16* p){
  return __builtin_bit_cast(bf16x8, *(const ushort8*)p);
}
__device__ __forceinline__ void gload16(const void* g, void* l){
  __builtin_amdgcn_global_load_lds((__attribute__((address_space(1))) void*)(void*)g,
                                   (__attribute__((address_space(3))) void*)l, 16, 0, 0);
}

// ---------------- convert / transpose ----------------

__global__ __launch_bounds__(256) void k_conv8(const float* __restrict__ in, u16* __restrict__ out){
  int i = blockIdx.x*256 + threadIdx.x;   // 393216 threads, 8 elems each
  const float4* p = (const float4*)in;
  float4 a = p[i*2], b = p[i*2+1];
  ushort8 o;
  o[0]=f2bf(a.x); o[1]=f2bf(a.y); o[2]=f2bf(a.z); o[3]=f2bf(a.w);
  o[4]=f2bf(b.x); o[5]=f2bf(b.y); o[6]=f2bf(b.z); o[7]=f2bf(b.w);
  ((ushort8*)out)[i] = o;
}

// out[c][r] = in[r][c], f32 -> bf16.  grid (R/64, C/64), 256 thr
__global__ __launch_bounds__(256) void k_tr(const float* __restrict__ in, u16* __restrict__ out,
                                            int R, int Cc){
  __shared__ float tile[64][65];
  int r0 = blockIdx.x*64, c0 = blockIdx.y*64;
  int t = threadIdx.x;
  int c = t & 63, r4 = t >> 6;
  for (int i = 0; i < 16; ++i)
    tile[r4 + i*4][c] = in[(size_t)(r0 + r4 + i*4)*Cc + c0 + c];
  __syncthreads();
  for (int i = 0; i < 16; ++i){
    int rr = r4 + i*4;
    out[(size_t)(c0 + rr)*R + r0 + c] = f2bf(tile[c][rr]);
  }
}

// rel_pos tables * 8 (undo the q-prescale; log2e rides in via Qs), bf16, padded to 128 rows
__global__ __launch_bounds__(256) void k_relconv(const float* __restrict__ rh, const float* __restrict__ rw,
                                                 u16* __restrict__ rh8, u16* __restrict__ rw8){
  int i = blockIdx.x*256 + threadIdx.x;   // 16384
  if (i < 8192)      rh8[i] = f2bf(i < 8128 ? rh[i]*8.0f : 0.0f);
  else { int j = i - 8192; rw8[j] = f2bf(j < 8128 ? rw[j]*8.0f : 0.0f); }
}

// ---------------- QKV GEMM: (4096x768)x(768x2304), split to Qs/Kf/Vf ----------------
// K and V are stored in MFMA-fragment-linear layout so every k_flash global load is
// a wave-contiguous 1KB burst:
//   Kf[h][kb][f=ct*2+ks][lane=lg*16+lr][e] = K[kb*64+ct*16+lr][ks*32+lg*8+e]
//   Vf[h][kb][f=dt*2+ks][lane=lg*16+lr][e] = V[kb*64+ks*32+lg*8+e][dt*16+lr]

__global__ __launch_bounds__(256) void k_qkv(const u16* __restrict__ X, const u16* __restrict__ WT,
                                             const float* __restrict__ bias,
                                             u16* __restrict__ Qs, u16* __restrict__ Kf, u16* __restrict__ Vf){
  __shared__ __align__(16) u16 At[128*64];
  __shared__ __align__(16) u16 Bt[128*64];
  const int tid = threadIdx.x, lane = tid & 63, w = tid >> 6;
  const int m0 = blockIdx.x*128, n0 = blockIdx.y*128;
  const int wr = (w >> 1)*64, wc = (w & 1)*64;
  const int lr = lane & 15, lg = lane >> 4;
  const int srcRow = w*32 + (lane >> 3);
  const int srcK   = (lane & 7)*8;
  f32x4 acc[4][4] = {};
  for (int kt = 0; kt < 12; ++kt){
    const int kbase = kt*64;
    for (int s = 0; s < 4; ++s){
      gload16(X  + (size_t)(m0 + srcRow + s*8)*768 + kbase + srcK, At + (w*32 + s*8)*64);
      gload16(WT + (size_t)(n0 + srcRow + s*8)*768 + kbase + srcK, Bt + (w*32 + s*8)*64);
    }
    __syncthreads();
    bf16x8 af[2][4], bfr[2][4];
    for (int ks = 0; ks < 2; ++ks)
      for (int i = 0; i < 4; ++i){
        af[ks][i]  = ld8(At + (wr + i*16 + lr)*64 + ks*32 + lg*8);
        bfr[ks][i] = ld8(Bt + (wc + i*16 + lr)*64 + ks*32 + lg*8);
      }
    for (int ks = 0; ks < 2; ++ks)
      for (int mi = 0; mi < 4; ++mi)
        for (int ni = 0; ni < 4; ++ni)
          acc[mi][ni] = MFMA(af[ks][mi], bfr[ks][ni], acc[mi][ni], 0, 0, 0);
    __syncthreads();
  }
  for (int mi = 0; mi < 4; ++mi)
    for (int ni = 0; ni < 4; ++ni){
      int col = n0 + wc + ni*16 + lr;
      int s3 = col / 768, rem = col % 768;
      int hh = rem >> 6, d = rem & 63;
      float bv = bias[col];
      for (int r = 0; r < 4; ++r){
        int row = m0 + wr + mi*16 + lg*4 + r;
        float v = acc[mi][ni][r] + bv;
        if (s3 == 0){
          // Q pre-scaled by head_dim^-0.5 * log2(e) so softmax runs in exp2 domain
          Qs[((size_t)hh*4096 + row)*64 + d] = f2bf(v*(0.125f*1.44269504f));
        } else {
          int kb = row >> 6, tt = row & 63;
          if (s3 == 1){
            int ct = tt >> 4, lr2 = tt & 15;
            int ks = d >> 5, lg2 = (d >> 3) & 3, e = d & 7;
            Kf[((((size_t)hh*64 + kb)*8 + ct*2 + ks)*64 + lg2*16 + lr2)*8 + e] = f2bf(v);
          } else {
            int ks = tt >> 5, lg2 = (tt >> 3) & 3, e = tt & 7;
            int dt = d >> 4, lr2 = d & 15;
            Vf[((((size_t)hh*64 + kb)*8 + dt*2 + ks)*64 + lg2*16 + lr2)*8 + e] = f2bf(v);
          }
        }
      }
    }
}

// ---------------- rel_h / rel_w via MFMA; grid (64 qh, 12 h) ----------------

__global__ __launch_bounds__(256) void k_rel(const u16* __restrict__ Qs, const u16* __restrict__ Rh8,
                                             const u16* __restrict__ Rw8,
                                             u16* __restrict__ relh, u16* __restrict__ relw){
  __shared__ __align__(16) u16 Ql[64*64];
  __shared__ __align__(16) u16 Rhl[64*64];
  __shared__ __align__(16) u16 Rwl[128*64];
  const int tid = threadIdx.x, lane = tid & 63, w = tid >> 6;
  const int qh = blockIdx.x, h = blockIdx.y;
  const int lr = lane & 15, lg = lane >> 4;
  for (int j = 0; j < 2; ++j){
    int ch = tid + 256*j;             // 0..511
    int row = ch >> 3, k8 = (ch & 7)*8;
    *(ushort8*)&Ql[row*64 + k8]  = *(const ushort8*)&Qs[((size_t)h*4096 + qh*64 + row)*64 + k8];
    *(ushort8*)&Rhl[row*64 + k8] = *(const ushort8*)&Rh8[(qh + row)*64 + k8];
  }
  for (int j = 0; j < 4; ++j){
    int ch = tid + 256*j;             // 0..1023
    int row = ch >> 3, k8 = (ch & 7)*8;
    *(ushort8*)&Rwl[row*64 + k8] = *(const ushort8*)&Rw8[row*64 + k8];
  }
  __syncthreads();
  bf16x8 a[2];
  for (int ks = 0; ks < 2; ++ks) a[ks] = ld8(Ql + (w*16 + lr)*64 + ks*32 + lg*8);
  // rel_h[qw][kh] = (Q . rel_pos_h[qh+63-kh]) ; computed as Q @ Rh[qh+c]^T, kh = 63-c
  for (int ct = 0; ct < 4; ++ct){
    f32x4 c = {};
    for (int ks = 0; ks < 2; ++ks)
      c = MFMA(a[ks], ld8(Rhl + (ct*16 + lr)*64 + ks*32 + lg*8), c, 0, 0, 0);
    int kh = 63 - (ct*16 + lr);
    for (int r = 0; r < 4; ++r){
      int qw = w*16 + lg*4 + r;
      relh[((size_t)h*4096 + qh*64 + qw)*64 + kh] = f2bf(c[r]);
    }
  }
  // rel_w[qw][kw] = (Q . rel_pos_w[qw+63-kw]) ; full band, keep valid kw
  for (int ct = 0; ct < 8; ++ct){
    f32x4 c = {};
    for (int ks = 0; ks < 2; ++ks)
      c = MFMA(a[ks], ld8(Rwl + (ct*16 + lr)*64 + ks*32 + lg*8), c, 0, 0, 0);
    int cc = ct*16 + lr;
    for (int r = 0; r < 4; ++r){
      int qw = w*16 + lg*4 + r;
      int kw = qw + 63 - cc;
      if (kw >= 0 && kw < 64)
        relw[((size_t)h*4096 + qh*64 + qw)*64 + kw] = f2bf(c[r]);
    }
  }
}

// ---------------- flash attention; grid (64 qblocks, 12 heads), 4 waves ----------------
// Swapped-operand layout: QK^T computed as mfma(K,Q) -> S^T (col = q = lane&15),
// softmax per-lane over 16 own values + two shfl_xor; PV as mfma(V^T,P^T) -> O^T.
// K/V read from fragment-linear global layout: each ld8 is a wave-contiguous 1KB burst.
// K double-buffered (next tile prefetched during softmax); V issued at iteration top.

__global__ __launch_bounds__(256, 3) void k_flash(const u16* __restrict__ Qs, const u16* __restrict__ Kf,
                                                  const u16* __restrict__ Vf,
                                                  const u16* __restrict__ relh, const u16* __restrict__ relw,
                                                  u16* __restrict__ Ob){
  __shared__ __align__(16) char SM[4][2048];   // per-wave P tile [16 q][64 k] bf16, XOR-swizzled
  const int tid = threadIdx.x, lane = tid & 63, w = tid >> 6;
  const int qb = blockIdx.x, h = blockIdx.y;
  const int lr = lane & 15, lg = lane >> 4;
  const size_t hq = (size_t)h*4096;
  const int q = qb*64 + w*16 + lr;             // this lane's q row (S^T column)
  char* Pb = SM[w];
  const int swz = (lr & 7) << 4;

  const bf16x8 qf0 = ld8(Qs + (hq + q)*64 + lg*8);
  const bf16x8 qf1 = ld8(Qs + (hq + q)*64 + 32 + lg*8);
  ushort4v rwp[4];
  #pragma unroll
  for (int ct = 0; ct < 4; ++ct)
    rwp[ct] = *(const ushort4v*)&relw[(hq + q)*64 + ct*16 + lg*4];

  const u16* KfH = Kf + (size_t)h*262144 + lane*8;   // + kb*4096 + f*512
  const u16* VfH = Vf + (size_t)h*262144 + lane*8;
  const u16* rhbase = relh + (hq + q)*64;

  float m = -1e30f, lsum = 0.f;
  f32x4 oacc[4] = {};                          // O^T tiles: rows d = dt*16+lg*4+r, col q = lr
  bf16x8 kA[8], kB[8], vv[8];

  auto loadK = [&](bf16x8 (&dst)[8], int kbi){
    const u16* kp = KfH + kbi*4096;
    #pragma unroll
    for (int f = 0; f < 8; ++f) dst[f] = ld8(kp + f*512);
  };
  auto iter = [&](int kb, const bf16x8 (&KC)[8], bf16x8 (&KN)[8]){
    // V for this tile: issue now, consumed after softmax
    const u16* vp = VfH + kb*4096;
    #pragma unroll
    for (int f = 0; f < 8; ++f) vv[f] = ld8(vp + f*512);
    // S^T = K·Q^T, acc pre-seeded with bias rel_h[q][kb] + rel_w[q][k]
    const float rhv = bf2f(rhbase[kb]);
    f32x4 s[4];
    #pragma unroll
    for (int ct = 0; ct < 4; ++ct)
      #pragma unroll
      for (int r = 0; r < 4; ++r)
        s[ct][r] = rhv + bf2f(rwp[ct][r]);
    #pragma unroll
    for (int ct = 0; ct < 4; ++ct){
      s[ct] = MFMA(KC[ct*2],   qf0, s[ct], 0, 0, 0);
      s[ct] = MFMA(KC[ct*2+1], qf1, s[ct], 0, 0, 0);
    }
    // prefetch next K tile; latency hides under softmax + P round-trip
    loadK(KN, (kb + 1) & 63);
    // per-lane softmax over this lane's 16 k-values, then reduce across lg
    float t0 = fmaxf(fmaxf(s[0][0], s[0][1]), fmaxf(s[0][2], s[0][3]));
    float t1 = fmaxf(fmaxf(s[1][0], s[1][1]), fmaxf(s[1][2], s[1][3]));
    float t2 = fmaxf(fmaxf(s[2][0], s[2][1]), fmaxf(s[2][2], s[2][3]));
    float t3 = fmaxf(fmaxf(s[3][0], s[3][1]), fmaxf(s[3][2], s[3][3]));
    float pm = fmaxf(fmaxf(t0, t1), fmaxf(t2, t3));
    pm = fmaxf(pm, __shfl_xor(pm, 16, 64));
    pm = fmaxf(pm, __shfl_xor(pm, 32, 64));
    const float nm = fmaxf(m, pm);
    const float corr = EXP2(m - nm);
    m = nm;
    float rs = 0.f;
    #pragma unroll
    for (int ct = 0; ct < 4; ++ct)
      #pragma unroll
      for (int r = 0; r < 4; ++r){
        float p = EXP2(s[ct][r] - m);
        s[ct][r] = p; rs += p;
      }
    rs += __shfl_xor(rs, 16, 64);
    rs += __shfl_xor(rs, 32, 64);
    lsum = lsum*corr + rs;
    #pragma unroll
    for (int dt = 0; dt < 4; ++dt)
      #pragma unroll
      for (int r = 0; r < 4; ++r) oacc[dt][r] *= corr;
    // P[q][k] -> LDS (packed b64 writes, XOR-swizzled), then read back as P^T b-frags
    #pragma unroll
    for (int ct = 0; ct < 4; ++ct){
      uint2 uv;
      uv.x = (uint32_t)f2bf(s[ct][0]) | ((uint32_t)f2bf(s[ct][1]) << 16);
      uv.y = (uint32_t)f2bf(s[ct][2]) | ((uint32_t)f2bf(s[ct][3]) << 16);
      *(uint2*)(Pb + ((lr*128 + ct*32 + lg*8) ^ swz)) = uv;
    }
    bf16x8 pa0 = __builtin_bit_cast(bf16x8, *(ushort8*)(Pb + ((lr*128      + lg*16) ^ swz)));
    bf16x8 pa1 = __builtin_bit_cast(bf16x8, *(ushort8*)(Pb + ((lr*128 + 64 + lg*16) ^ swz)));
    // O^T += V^T · P^T
    #pragma unroll
    for (int dt = 0; dt < 4; ++dt){
      oacc[dt] = MFMA(vv[dt*2],   pa0, oacc[dt], 0, 0, 0);
      oacc[dt] = MFMA(vv[dt*2+1], pa1, oacc[dt], 0, 0, 0);
    }
  };

  loadK(kA, 0);
  for (int kb2 = 0; kb2 < 64; kb2 += 2){
    iter(kb2,     kA, kB);
    iter(kb2 + 1, kB, kA);
  }

  const float inv = 1.0f / lsum;
  #pragma unroll
  for (int dt = 0; dt < 4; ++dt){
    ushort4v pk;
    #pragma unroll
    for (int r = 0; r < 4; ++r) pk[r] = f2bf(oacc[dt][r]*inv);
    *(ushort4v*)&Ob[(size_t)q*768 + h*64 + dt*16 + lg*4] = pk;
  }
}

// ---------------- proj GEMM: (4096x768)x(768x768) + b -> f32 out ----------------

__global__ __launch_bounds__(256) void k_proj(const u16* __restrict__ A, const u16* __restrict__ WT,
                                              const float* __restrict__ bias, float* __restrict__ out){
  __shared__ __align__(16) u16 At[128*64];
  __shared__ __align__(16) u16 Bt[128*64];
  const int tid = threadIdx.x, lane = tid & 63, w = tid >> 6;
  const int m0 = blockIdx.x*128, n0 = blockIdx.y*128;
  const int wr = (w >> 1)*64, wc = (w & 1)*64;
  const int lr = lane & 15, lg = lane >> 4;
  const int srcRow = w*32 + (lane >> 3);
  const int srcK   = (lane & 7)*8;
  f32x4 acc[4][4] = {};
  for (int kt = 0; kt < 12; ++kt){
    const int kbase = kt*64;
    for (int s = 0; s < 4; ++s){
      gload16(A  + (size_t)(m0 + srcRow + s*8)*768 + kbase + srcK, At + (w*32 + s*8)*64);
      gload16(WT + (size_t)(n0 + srcRow + s*8)*768 + kbase + srcK, Bt + (w*32 + s*8)*64);
    }
    __syncthreads();
    bf16x8 af[2][4], bfr[2][4];
    for (int ks = 0; ks < 2; ++ks)
      for (int i = 0; i < 4; ++i){
        af[ks][i]  = ld8(At + (wr + i*16 + lr)*64 + ks*32 + lg*8);
        bfr[ks][i] = ld8(Bt + (wc + i*16 + lr)*64 + ks*32 + lg*8);
      }
    for (int ks = 0; ks < 2; ++ks)
      for (int mi = 0; mi < 4; ++mi)
        for (int ni = 0; ni < 4; ++ni)
          acc[mi][ni] = MFMA(af[ks][mi], bfr[ks][ni], acc[mi][ni], 0, 0, 0);
    __syncthreads();
  }
  for (int mi = 0; mi < 4; ++mi)
    for (int ni = 0; ni < 4; ++ni){
      int col = n0 + wc + ni*16 + lr;
      float bv = bias[col];
      for (int r = 0; r < 4; ++r){
        int row = m0 + wr + mi*16 + lg*4 + r;
        out[(size_t)row*768 + col] = acc[mi][ni][r] + bv;
      }
    }
}

// ---------------- launch ----------------

extern "C" void kernel_launch(void* const* d_in, const int* in_sizes, int n_in,
                              void* d_out, int out_size, void* d_ws, size_t ws_size,
                              hipStream_t stream){
  const float* X32   = (const float*)d_in[0];
  const float* qkvw  = (const float*)d_in[1];
  const float* qkvb  = (const float*)d_in[2];
  const float* projw = (const float*)d_in[3];
  const float* projb = (const float*)d_in[4];
  const float* rposh = (const float*)d_in[5];
  const float* rposw = (const float*)d_in[6];

  u16* Xb  = (u16*)d_ws;            // 4096*768
  u16* W1T = Xb  + 3145728;         // 2304*768
  u16* PT  = W1T + 1769472;         // 768*768
  u16* Rh8 = PT  + 589824;          // 128*64 (padded)
  u16* Rw8 = Rh8 + 8192;            // 128*64 (padded)
  u16* Qs  = Rw8 + 8192;            // 12*4096*64 (pre-scaled by 1/8 * log2e)
  u16* Kf  = Qs  + 3145728;         // fragment-linear K [12][64][8][64][8]
  u16* Vf  = Kf  + 3145728;         // fragment-linear V^T [12][64][8][64][8]
  u16* Rlh = Vf  + 3145728;         // [12][4096][64]
  u16* Rlw = Rlh + 3145728;         // [12][4096][64]
  u16* Ob  = Rlw + 3145728;         // [4096][768]
  float* out = (float*)d_out;

  k_conv8  <<<1536, 256, 0, stream>>>(X32, Xb);
  k_tr     <<<dim3(12, 36), 256, 0, stream>>>(qkvw, W1T, 768, 2304);
  k_tr     <<<dim3(12, 12), 256, 0, stream>>>(projw, PT, 768, 768);
  k_relconv<<<64, 256, 0, stream>>>(rposh, rposw, Rh8, Rw8);
  k_qkv    <<<dim3(32, 18), 256, 0, stream>>>(Xb, W1T, qkvb, Qs, Kf, Vf);
  k_rel    <<<dim3(64, 12), 256, 0, stream>>>(Qs, Rh8, Rw8, Rlh, Rlw);
  k_flash  <<<dim3(64, 12), 256, 0, stream>>>(Qs, Kf, Vf, Rlh, Rlw, Ob);
  k_proj   <<<dim3(32, 6), 256, 0, stream>>>(Ob, PT, projb, out);
}

// Round 5
// 192.900 us; speedup vs baseline: 4.6693x; 2.2419x over previous
//
#include <hip/hip_runtime.h>
#include <stdint.h>

typedef unsigned short u16;
typedef __bf16 bf16x8 __attribute__((ext_vector_type(8)));
typedef float f32x4 __attribute__((ext_vector_type(4)));
typedef unsigned short ushort8 __attribute__((ext_vector_type(8)));
typedef unsigned short ushort4v __attribute__((ext_vector_type(4)));

#define MFMA __builtin_amdgcn_mfma_f32_16x16x32_bf16
#define EXP2 __builtin_amdgcn_exp2f

__device__ __forceinline__ u16 f2bf(float f){
  uint32_t u = __builtin_bit_cast(uint32_t, f);
  u += 0x7fffu + ((u >> 16) & 1u);
  return (u16)(u >> 16);
}
__device__ __forceinline__ float bf2f(u16 h){
  uint32_t u = ((uint32_t)h) << 16;
  return __builtin_bit_cast(float, u);
}
__device__ __forceinline__ bf16x8 ld8(const u16* p){
  return __builtin_bit_cast(bf16x8, *(const ushort8*)p);
}
__device__ __forceinline__ void gload16(const void* g, void* l){
  __builtin_amdgcn_global_load_lds((__attribute__((address_space(1))) void*)(void*)g,
                                   (__attribute__((address_space(3))) void*)l, 16, 0, 0);
}

// ---------------- convert / transpose ----------------

__global__ __launch_bounds__(256) void k_conv8(const float* __restrict__ in, u16* __restrict__ out){
  int i = blockIdx.x*256 + threadIdx.x;   // 393216 threads, 8 elems each
  const float4* p = (const float4*)in;
  float4 a = p[i*2], b = p[i*2+1];
  ushort8 o;
  o[0]=f2bf(a.x); o[1]=f2bf(a.y); o[2]=f2bf(a.z); o[3]=f2bf(a.w);
  o[4]=f2bf(b.x); o[5]=f2bf(b.y); o[6]=f2bf(b.z); o[7]=f2bf(b.w);
  ((ushort8*)out)[i] = o;
}

// out[c][r] = in[r][c], f32 -> bf16.  grid (R/64, C/64), 256 thr
__global__ __launch_bounds__(256) void k_tr(const float* __restrict__ in, u16* __restrict__ out,
                                            int R, int Cc){
  __shared__ float tile[64][65];
  int r0 = blockIdx.x*64, c0 = blockIdx.y*64;
  int t = threadIdx.x;
  int c = t & 63, r4 = t >> 6;
  for (int i = 0; i < 16; ++i)
    tile[r4 + i*4][c] = in[(size_t)(r0 + r4 + i*4)*Cc + c0 + c];
  __syncthreads();
  for (int i = 0; i < 16; ++i){
    int rr = r4 + i*4;
    out[(size_t)(c0 + rr)*R + r0 + c] = f2bf(tile[c][rr]);
  }
}

// rel_pos tables * 8 (undo the q-prescale; log2e rides in via Qs), bf16, padded to 128 rows
__global__ __launch_bounds__(256) void k_relconv(const float* __restrict__ rh, const float* __restrict__ rw,
                                                 u16* __restrict__ rh8, u16* __restrict__ rw8){
  int i = blockIdx.x*256 + threadIdx.x;   // 16384
  if (i < 8192)      rh8[i] = f2bf(i < 8128 ? rh[i]*8.0f : 0.0f);
  else { int j = i - 8192; rw8[j] = f2bf(j < 8128 ? rw[j]*8.0f : 0.0f); }
}

// ---------------- QKV GEMM: (4096x768)x(768x2304), split to Qs/Kf/Vf ----------------
// K/V stored fragment-linear so every k_flash global load is a wave-contiguous 1KB burst:
//   Kf[h][kb][f=ct*2+ks][lane=lg*16+lr][e] = K[kb*64+ct*16+lr][ks*32+lg*8+e]
//   Vf[h][kb][f=dt*2+ks][lane=lg*16+lr][e] = V[kb*64+ks*32+lg*8+e][dt*16+lr]
// Each wave's 64x64 acc tile is exactly one Kf[h][kb] / Vf[h][kb] 4KB block
// (row/col bases 64-aligned), so repack goes through a per-wave LDS tile:
// scalar LDS writes (V transposed), then 8x16B coalesced global bursts.

__global__ __launch_bounds__(256) void k_qkv(const u16* __restrict__ X, const u16* __restrict__ WT,
                                             const float* __restrict__ bias,
                                             u16* __restrict__ Qs, u16* __restrict__ Kf, u16* __restrict__ Vf){
  __shared__ __align__(16) u16 At[128*64];
  __shared__ __align__(16) u16 Bt[128*64];
  __shared__ __align__(16) u16 Tt[4][64*72];   // per-wave repack tile, pad 72 keeps 16B align
  const int tid = threadIdx.x, lane = tid & 63, w = tid >> 6;
  const int m0 = blockIdx.x*128, n0 = blockIdx.y*128;
  const int wr = (w >> 1)*64, wc = (w & 1)*64;
  const int lr = lane & 15, lg = lane >> 4;
  const int srcRow = w*32 + (lane >> 3);
  const int srcK   = (lane & 7)*8;
  f32x4 acc[4][4] = {};
  for (int kt = 0; kt < 12; ++kt){
    const int kbase = kt*64;
    for (int s = 0; s < 4; ++s){
      gload16(X  + (size_t)(m0 + srcRow + s*8)*768 + kbase + srcK, At + (w*32 + s*8)*64);
      gload16(WT + (size_t)(n0 + srcRow + s*8)*768 + kbase + srcK, Bt + (w*32 + s*8)*64);
    }
    __syncthreads();
    bf16x8 af[2][4], bfr[2][4];
    for (int ks = 0; ks < 2; ++ks)
      for (int i = 0; i < 4; ++i){
        af[ks][i]  = ld8(At + (wr + i*16 + lr)*64 + ks*32 + lg*8);
        bfr[ks][i] = ld8(Bt + (wc + i*16 + lr)*64 + ks*32 + lg*8);
      }
    for (int ks = 0; ks < 2; ++ks)
      for (int mi = 0; mi < 4; ++mi)
        for (int ni = 0; ni < 4; ++ni)
          acc[mi][ni] = MFMA(af[ks][mi], bfr[ks][ni], acc[mi][ni], 0, 0, 0);
    __syncthreads();
  }
  const int colbase = n0 + wc;            // 64-aligned -> s3/hh uniform per wave
  const int s3 = colbase / 768;
  const int hh = (colbase % 768) >> 6;
  const int rowbase = m0 + wr;            // 64-aligned -> kb uniform per wave
  if (s3 == 0){
    for (int mi = 0; mi < 4; ++mi)
      for (int ni = 0; ni < 4; ++ni){
        float bv = bias[colbase + ni*16 + lr];
        for (int r = 0; r < 4; ++r){
          int row = rowbase + mi*16 + lg*4 + r;
          // Q pre-scaled by head_dim^-0.5 * log2(e) so softmax runs in exp2 domain
          Qs[((size_t)hh*4096 + row)*64 + ni*16 + lr] =
              f2bf((acc[mi][ni][r] + bv)*(0.125f*1.44269504f));
        }
      }
  } else {
    u16* T = Tt[w];
    for (int mi = 0; mi < 4; ++mi)
      for (int ni = 0; ni < 4; ++ni){
        float bv = bias[colbase + ni*16 + lr];
        for (int r = 0; r < 4; ++r){
          int row_l = mi*16 + lg*4 + r, col_l = ni*16 + lr;
          u16 v = f2bf(acc[mi][ni][r] + bv);
          if (s3 == 1) T[row_l*72 + col_l] = v;     // K: [token][d]
          else         T[col_l*72 + row_l] = v;     // V: [d][token] (transposed)
        }
      }
    // same-wave LDS write->read; no cross-wave sharing, compiler inserts lgkmcnt
    const int kb = rowbase >> 6;
    u16* dst = (s3 == 1 ? Kf : Vf) + ((size_t)hh*64 + kb)*4096 + lane*8;
    #pragma unroll
    for (int f = 0; f < 8; ++f){
      int a = f >> 1, ks = f & 1;
      *(ushort8*)&dst[f*512] = *(const ushort8*)&T[(a*16 + lr)*72 + ks*32 + lg*8];
    }
  }
}

// ---------------- rel_h / rel_w via MFMA; grid (64 qh, 12 h) ----------------

__global__ __launch_bounds__(256) void k_rel(const u16* __restrict__ Qs, const u16* __restrict__ Rh8,
                                             const u16* __restrict__ Rw8,
                                             u16* __restrict__ relh, u16* __restrict__ relw){
  __shared__ __align__(16) u16 Ql[64*64];
  __shared__ __align__(16) u16 Rhl[64*64];
  __shared__ __align__(16) u16 Rwl[128*64];
  const int tid = threadIdx.x, lane = tid & 63, w = tid >> 6;
  const int qh = blockIdx.x, h = blockIdx.y;
  const int lr = lane & 15, lg = lane >> 4;
  for (int j = 0; j < 2; ++j){
    int ch = tid + 256*j;             // 0..511
    int row = ch >> 3, k8 = (ch & 7)*8;
    *(ushort8*)&Ql[row*64 + k8]  = *(const ushort8*)&Qs[((size_t)h*4096 + qh*64 + row)*64 + k8];
    *(ushort8*)&Rhl[row*64 + k8] = *(const ushort8*)&Rh8[(qh + row)*64 + k8];
  }
  for (int j = 0; j < 4; ++j){
    int ch = tid + 256*j;             // 0..1023
    int row = ch >> 3, k8 = (ch & 7)*8;
    *(ushort8*)&Rwl[row*64 + k8] = *(const ushort8*)&Rw8[row*64 + k8];
  }
  __syncthreads();
  bf16x8 a[2];
  for (int ks = 0; ks < 2; ++ks) a[ks] = ld8(Ql + (w*16 + lr)*64 + ks*32 + lg*8);
  // rel_h[qw][kh] = (Q . rel_pos_h[qh+63-kh]) ; computed as Q @ Rh[qh+c]^T, kh = 63-c
  for (int ct = 0; ct < 4; ++ct){
    f32x4 c = {};
    for (int ks = 0; ks < 2; ++ks)
      c = MFMA(a[ks], ld8(Rhl + (ct*16 + lr)*64 + ks*32 + lg*8), c, 0, 0, 0);
    int kh = 63 - (ct*16 + lr);
    for (int r = 0; r < 4; ++r){
      int qw = w*16 + lg*4 + r;
      relh[((size_t)h*4096 + qh*64 + qw)*64 + kh] = f2bf(c[r]);
    }
  }
  // rel_w[qw][kw] = (Q . rel_pos_w[qw+63-kw]) ; full band, keep valid kw
  for (int ct = 0; ct < 8; ++ct){
    f32x4 c = {};
    for (int ks = 0; ks < 2; ++ks)
      c = MFMA(a[ks], ld8(Rwl + (ct*16 + lr)*64 + ks*32 + lg*8), c, 0, 0, 0);
    int cc = ct*16 + lr;
    for (int r = 0; r < 4; ++r){
      int qw = w*16 + lg*4 + r;
      int kw = qw + 63 - cc;
      if (kw >= 0 && kw < 64)
        relw[((size_t)h*4096 + qh*64 + qw)*64 + kw] = f2bf(c[r]);
    }
  }
}

// ---------------- flash attention; flat grid 768, 4 waves ----------------
// Head->XCD affinity: xcd = b&7 gets 96 consecutive (h,qb) pairs -> <=2 heads/XCD
// -> KV working set 2MB fits the 4MB per-XCD L2 (loads ~200cy instead of L3 ~600cy).
// Swapped-operand: QK^T as mfma(K,Q) -> S^T; PV as mfma(V^T,P^T) -> O^T.
// K/V fragment-linear: each ld8 is a wave-contiguous 1KB burst. K double-buffered.

__global__ __launch_bounds__(256, 3) void k_flash(const u16* __restrict__ Qs, const u16* __restrict__ Kf,
                                                  const u16* __restrict__ Vf,
                                                  const u16* __restrict__ relh, const u16* __restrict__ relw,
                                                  u16* __restrict__ Ob){
  __shared__ __align__(16) char SM[4][2048];   // per-wave P tile [16 q][64 k] bf16, XOR-swizzled
  const int tid = threadIdx.x, lane = tid & 63, w = tid >> 6;
  const int b = blockIdx.x;
  const int p = (b & 7)*96 + (b >> 3);         // head->XCD affinity remap
  const int h = p >> 6, qb = p & 63;
  const int lr = lane & 15, lg = lane >> 4;
  const size_t hq = (size_t)h*4096;
  const int q = qb*64 + w*16 + lr;             // this lane's q row (S^T column)
  char* Pb = SM[w];
  const int swz = (lr & 7) << 4;

  const bf16x8 qf0 = ld8(Qs + (hq + q)*64 + lg*8);
  const bf16x8 qf1 = ld8(Qs + (hq + q)*64 + 32 + lg*8);
  ushort4v rwp[4];
  #pragma unroll
  for (int ct = 0; ct < 4; ++ct)
    rwp[ct] = *(const ushort4v*)&relw[(hq + q)*64 + ct*16 + lg*4];

  const u16* KfH = Kf + (size_t)h*262144 + lane*8;   // + kb*4096 + f*512
  const u16* VfH = Vf + (size_t)h*262144 + lane*8;
  const u16* rhbase = relh + (hq + q)*64;

  float m = -1e30f, lsum = 0.f;
  f32x4 oacc[4] = {};                          // O^T tiles: rows d = dt*16+lg*4+r, col q = lr
  bf16x8 kA[8], kB[8], vv[8];

  auto loadK = [&](bf16x8 (&dst)[8], int kbi){
    const u16* kp = KfH + kbi*4096;
    #pragma unroll
    for (int f = 0; f < 8; ++f) dst[f] = ld8(kp + f*512);
  };
  auto iter = [&](int kb, const bf16x8 (&KC)[8], bf16x8 (&KN)[8]){
    // V for this tile: issue now, consumed after softmax
    const u16* vp = VfH + kb*4096;
    #pragma unroll
    for (int f = 0; f < 8; ++f) vv[f] = ld8(vp + f*512);
    // S^T = K·Q^T, acc pre-seeded with bias rel_h[q][kb] + rel_w[q][k]
    const float rhv = bf2f(rhbase[kb]);
    f32x4 s[4];
    #pragma unroll
    for (int ct = 0; ct < 4; ++ct)
      #pragma unroll
      for (int r = 0; r < 4; ++r)
        s[ct][r] = rhv + bf2f(rwp[ct][r]);
    __builtin_amdgcn_s_setprio(1);
    #pragma unroll
    for (int ct = 0; ct < 4; ++ct){
      s[ct] = MFMA(KC[ct*2],   qf0, s[ct], 0, 0, 0);
      s[ct] = MFMA(KC[ct*2+1], qf1, s[ct], 0, 0, 0);
    }
    __builtin_amdgcn_s_setprio(0);
    // prefetch next K tile; latency hides under softmax + P round-trip
    loadK(KN, (kb + 1) & 63);
    // per-lane softmax over this lane's 16 k-values, then reduce across lg
    float t0 = fmaxf(fmaxf(s[0][0], s[0][1]), fmaxf(s[0][2], s[0][3]));
    float t1 = fmaxf(fmaxf(s[1][0], s[1][1]), fmaxf(s[1][2], s[1][3]));
    float t2 = fmaxf(fmaxf(s[2][0], s[2][1]), fmaxf(s[2][2], s[2][3]));
    float t3 = fmaxf(fmaxf(s[3][0], s[3][1]), fmaxf(s[3][2], s[3][3]));
    float pm = fmaxf(fmaxf(t0, t1), fmaxf(t2, t3));
    pm = fmaxf(pm, __shfl_xor(pm, 16, 64));
    pm = fmaxf(pm, __shfl_xor(pm, 32, 64));
    const float nm = fmaxf(m, pm);
    const float corr = EXP2(m - nm);
    m = nm;
    float rs = 0.f;
    #pragma unroll
    for (int ct = 0; ct < 4; ++ct)
      #pragma unroll
      for (int r = 0; r < 4; ++r){
        float p2 = EXP2(s[ct][r] - m);
        s[ct][r] = p2; rs += p2;
      }
    rs += __shfl_xor(rs, 16, 64);
    rs += __shfl_xor(rs, 32, 64);
    lsum = lsum*corr + rs;
    #pragma unroll
    for (int dt = 0; dt < 4; ++dt)
      #pragma unroll
      for (int r = 0; r < 4; ++r) oacc[dt][r] *= corr;
    // P[q][k] -> LDS (packed b64 writes, XOR-swizzled), then read back as P^T b-frags
    #pragma unroll
    for (int ct = 0; ct < 4; ++ct){
      uint2 uv;
      uv.x = (uint32_t)f2bf(s[ct][0]) | ((uint32_t)f2bf(s[ct][1]) << 16);
      uv.y = (uint32_t)f2bf(s[ct][2]) | ((uint32_t)f2bf(s[ct][3]) << 16);
      *(uint2*)(Pb + ((lr*128 + ct*32 + lg*8) ^ swz)) = uv;
    }
    bf16x8 pa0 = __builtin_bit_cast(bf16x8, *(ushort8*)(Pb + ((lr*128      + lg*16) ^ swz)));
    bf16x8 pa1 = __builtin_bit_cast(bf16x8, *(ushort8*)(Pb + ((lr*128 + 64 + lg*16) ^ swz)));
    // O^T += V^T · P^T
    __builtin_amdgcn_s_setprio(1);
    #pragma unroll
    for (int dt = 0; dt < 4; ++dt){
      oacc[dt] = MFMA(vv[dt*2],   pa0, oacc[dt], 0, 0, 0);
      oacc[dt] = MFMA(vv[dt*2+1], pa1, oacc[dt], 0, 0, 0);
    }
    __builtin_amdgcn_s_setprio(0);
  };

  loadK(kA, 0);
  for (int kb2 = 0; kb2 < 64; kb2 += 2){
    iter(kb2,     kA, kB);
    iter(kb2 + 1, kB, kA);
  }

  const float inv = 1.0f / lsum;
  #pragma unroll
  for (int dt = 0; dt < 4; ++dt){
    ushort4v pk;
    #pragma unroll
    for (int r = 0; r < 4; ++r) pk[r] = f2bf(oacc[dt][r]*inv);
    *(ushort4v*)&Ob[(size_t)q*768 + h*64 + dt*16 + lg*4] = pk;
  }
}

// ---------------- proj GEMM: (4096x768)x(768x768) + b -> f32 out ----------------

__global__ __launch_bounds__(256) void k_proj(const u16* __restrict__ A, const u16* __restrict__ WT,
                                              const float* __restrict__ bias, float* __restrict__ out){
  __shared__ __align__(16) u16 At[128*64];
  __shared__ __align__(16) u16 Bt[128*64];
  const int tid = threadIdx.x, lane = tid & 63, w = tid >> 6;
  const int m0 = blockIdx.x*128, n0 = blockIdx.y*128;
  const int wr = (w >> 1)*64, wc = (w & 1)*64;
  const int lr = lane & 15, lg = lane >> 4;
  const int srcRow = w*32 + (lane >> 3);
  const int srcK   = (lane & 7)*8;
  f32x4 acc[4][4] = {};
  for (int kt = 0; kt < 12; ++kt){
    const int kbase = kt*64;
    for (int s = 0; s < 4; ++s){
      gload16(A  + (size_t)(m0 + srcRow + s*8)*768 + kbase + srcK, At + (w*32 + s*8)*64);
      gload16(WT + (size_t)(n0 + srcRow + s*8)*768 + kbase + srcK, Bt + (w*32 + s*8)*64);
    }
    __syncthreads();
    bf16x8 af[2][4], bfr[2][4];
    for (int ks = 0; ks < 2; ++ks)
      for (int i = 0; i < 4; ++i){
        af[ks][i]  = ld8(At + (wr + i*16 + lr)*64 + ks*32 + lg*8);
        bfr[ks][i] = ld8(Bt + (wc + i*16 + lr)*64 + ks*32 + lg*8);
      }
    for (int ks = 0; ks < 2; ++ks)
      for (int mi = 0; mi < 4; ++mi)
        for (int ni = 0; ni < 4; ++ni)
          acc[mi][ni] = MFMA(af[ks][mi], bfr[ks][ni], acc[mi][ni], 0, 0, 0);
    __syncthreads();
  }
  for (int mi = 0; mi < 4; ++mi)
    for (int ni = 0; ni < 4; ++ni){
      int col = n0 + wc + ni*16 + lr;
      float bv = bias[col];
      for (int r = 0; r < 4; ++r){
        int row = m0 + wr + mi*16 + lg*4 + r;
        out[(size_t)row*768 + col] = acc[mi][ni][r] + bv;
      }
    }
}

// ---------------- launch ----------------

extern "C" void kernel_launch(void* const* d_in, const int* in_sizes, int n_in,
                              void* d_out, int out_size, void* d_ws, size_t ws_size,
                              hipStream_t stream){
  const float* X32   = (const float*)d_in[0];
  const float* qkvw  = (const float*)d_in[1];
  const float* qkvb  = (const float*)d_in[2];
  const float* projw = (const float*)d_in[3];
  const float* projb = (const float*)d_in[4];
  const float* rposh = (const float*)d_in[5];
  const float* rposw = (const float*)d_in[6];

  u16* Xb  = (u16*)d_ws;            // 4096*768
  u16* W1T = Xb  + 3145728;         // 2304*768
  u16* PT  = W1T + 1769472;         // 768*768
  u16* Rh8 = PT  + 589824;          // 128*64 (padded)
  u16* Rw8 = Rh8 + 8192;            // 128*64 (padded)
  u16* Qs  = Rw8 + 8192;            // 12*4096*64 (pre-scaled by 1/8 * log2e)
  u16* Kf  = Qs  + 3145728;         // fragment-linear K [12][64][8][64][8]
  u16* Vf  = Kf  + 3145728;         // fragment-linear V^T [12][64][8][64][8]
  u16* Rlh = Vf  + 3145728;         // [12][4096][64]
  u16* Rlw = Rlh + 3145728;         // [12][4096][64]
  u16* Ob  = Rlw + 3145728;         // [4096][768]
  float* out = (float*)d_out;

  k_conv8  <<<1536, 256, 0, stream>>>(X32, Xb);
  k_tr     <<<dim3(12, 36), 256, 0, stream>>>(qkvw, W1T, 768, 2304);
  k_tr     <<<dim3(12, 12), 256, 0, stream>>>(projw, PT, 768, 768);
  k_relconv<<<64, 256, 0, stream>>>(rposh, rposw, Rh8, Rw8);
  k_qkv    <<<dim3(32, 18), 256, 0, stream>>>(Xb, W1T, qkvb, Qs, Kf, Vf);
  k_rel    <<<dim3(64, 12), 256, 0, stream>>>(Qs, Rh8, Rw8, Rlh, Rlw);
  k_flash  <<<768, 256, 0, stream>>>(Qs, Kf, Vf, Rlh, Rlw, Ob);
  k_proj   <<<dim3(32, 6), 256, 0, stream>>>(Ob, PT, projb, out);
}